// Round 5
// baseline (230.085 us; speedup 1.0000x reference)
//
#include <hip/hip_runtime.h>
#include <math.h>

#define F_IN 256
#define OUT  64
#define LEAKY 0.2f

typedef __attribute__((ext_vector_type(4))) float f32x4;
typedef __attribute__((ext_vector_type(8))) __bf16 bf16x8;
typedef __attribute__((ext_vector_type(4))) unsigned int u32x4;

__device__ __forceinline__ unsigned cvt_pk_bf16(float lo, float hi) {
    unsigned r;
    asm volatile("v_cvt_pk_bf16_f32 %0, %1, %2" : "=v"(r) : "v"(lo), "v"(hi));
    return r;
}

__device__ __forceinline__ float bf16bits_to_f32(unsigned short u) {
    return __builtin_bit_cast(float, (unsigned)u << 16);
}

__device__ __forceinline__ void gload_lds16(const float* g, float* l) {
    __builtin_amdgcn_global_load_lds((const __attribute__((address_space(1))) void*)g,
                                     (__attribute__((address_space(3))) void*)l, 16, 0, 0);
}

// ---------------- MFMA GEMM h = x@W (bf16 in, fp32 acc), fused f1/f2; h stored bf16 ----------------
__global__ __launch_bounds__(256) void gemm_f12_kernel(
    const float* __restrict__ x, const float* __restrict__ W,
    const float* __restrict__ a1, const float* __restrict__ b1,
    const float* __restrict__ a2, const float* __restrict__ b2,
    unsigned short* __restrict__ h2, float* __restrict__ f1, float* __restrict__ f2,
    int N)
{
    __shared__ __align__(16) unsigned int Wt[64 * 128];   // 64 cols x 256 k bf16 = 32 KB
    __shared__ __align__(16) float xs[2][128 * 32];       // 2 x 16 KB

    const int t    = threadIdx.x;
    const int wave = t >> 6;
    const int lane = t & 63;
    const int rowB = blockIdx.x * 128;

    for (int p = t; p < 64 * 32; p += 256) {
        int c = p & 63, g = p >> 6;
        float f[8];
#pragma unroll
        for (int j = 0; j < 8; ++j) f[j] = W[(g * 8 + j) * 64 + c];
        u32x4 d;
        d.x = cvt_pk_bf16(f[0], f[1]);
        d.y = cvt_pk_bf16(f[2], f[3]);
        d.z = cvt_pk_bf16(f[4], f[5]);
        d.w = cvt_pk_bf16(f[6], f[7]);
        int gs = g ^ (c & 7);
        *(u32x4*)&Wt[c * 128 + gs * 4] = d;
    }

    auto stage = [&](int buf, int kc) {
#pragma unroll
        for (int i = 0; i < 4; ++i) {
            int row  = i * 32 + wave * 8 + (lane >> 3);
            int g    = lane & 7;
            int srow = rowB + row; if (srow > N - 1) srow = N - 1;
            int gsw  = g ^ (row & 7);
            const float* src = x + (size_t)srow * F_IN + kc + gsw * 4;
            gload_lds16(src, &xs[buf][i * 1024 + wave * 256]);
        }
    };

    f32x4 acc[2][4];
#pragma unroll
    for (int m = 0; m < 2; ++m)
#pragma unroll
        for (int n = 0; n < 4; ++n) acc[m][n] = (f32x4){0.f, 0.f, 0.f, 0.f};

    stage(0, 0);
    asm volatile("s_waitcnt vmcnt(0)" ::: "memory");
    __syncthreads();

    for (int ks = 0; ks < 8; ++ks) {
        int cur = ks & 1;
        if (ks < 7) stage(cur ^ 1, (ks + 1) * 32);

        bf16x8 bfrag[4];
#pragma unroll
        for (int ns = 0; ns < 4; ++ns) {
            int c = ns * 16 + (lane & 15);
            int G = ks * 4 + (lane >> 4);
            u32x4 bw = *(u32x4*)&Wt[c * 128 + ((G ^ (c & 7)) << 2)];
            bfrag[ns] = __builtin_bit_cast(bf16x8, bw);
        }
#pragma unroll
        for (int ms = 0; ms < 2; ++ms) {
            int wrow = wave * 32 + ms * 16 + (lane & 15);
            int g0   = (lane >> 4) * 2;
            float4 xa = *(float4*)&xs[cur][wrow * 32 + (((g0 + 0) ^ (wrow & 7)) << 2)];
            float4 xb = *(float4*)&xs[cur][wrow * 32 + (((g0 + 1) ^ (wrow & 7)) << 2)];
            u32x4 ad;
            ad.x = cvt_pk_bf16(xa.x, xa.y);
            ad.y = cvt_pk_bf16(xa.z, xa.w);
            ad.z = cvt_pk_bf16(xb.x, xb.y);
            ad.w = cvt_pk_bf16(xb.z, xb.w);
            bf16x8 afrag = __builtin_bit_cast(bf16x8, ad);
#pragma unroll
            for (int ns = 0; ns < 4; ++ns)
                acc[ms][ns] = __builtin_amdgcn_mfma_f32_16x16x32_bf16(afrag, bfrag[ns],
                                                                      acc[ms][ns], 0, 0, 0);
        }
        asm volatile("s_waitcnt vmcnt(0)" ::: "memory");
        __syncthreads();
    }

    float A1v[4], A2v[4];
#pragma unroll
    for (int ns = 0; ns < 4; ++ns) {
        A1v[ns] = a1[ns * 16 + (lane & 15)];
        A2v[ns] = a2[ns * 16 + (lane & 15)];
    }
    float B1 = b1[0], B2 = b2[0];
#pragma unroll
    for (int ms = 0; ms < 2; ++ms) {
#pragma unroll
        for (int r = 0; r < 4; ++r) {
            int grow = rowB + wave * 32 + ms * 16 + ((lane >> 4) << 2) + r;
            float s1 = 0.f, s2 = 0.f;
#pragma unroll
            for (int ns = 0; ns < 4; ++ns) {
                float v = acc[ms][ns][r];
                if (grow < N)
                    h2[(size_t)grow * OUT + ns * 16 + (lane & 15)] =
                        (unsigned short)(cvt_pk_bf16(v, v) & 0xffffu);
                s1 += v * A1v[ns];
                s2 += v * A2v[ns];
            }
#pragma unroll
            for (int off = 1; off < 16; off <<= 1) {
                s1 += __shfl_xor(s1, off);
                s2 += __shfl_xor(s2, off);
            }
            if ((lane & 15) == 0 && grow < N) { f1[grow] = s1 + B1; f2[grow] = s2 + B2; }
        }
    }
}

// ---------------- CSR build: count + per-edge rank (fused) ----------------
__global__ __launch_bounds__(256) void count_rank_kernel(const int* __restrict__ src,
                                                         int* __restrict__ counts,
                                                         int* __restrict__ rank, int E)
{
    int i = (blockIdx.x * 256 + threadIdx.x) * 4;
    if (i + 4 <= E) {
        int4 s = *(const int4*)&src[i];
        int4 r;
        r.x = atomicAdd(&counts[s.x], 1);
        r.y = atomicAdd(&counts[s.y], 1);
        r.z = atomicAdd(&counts[s.z], 1);
        r.w = atomicAdd(&counts[s.w], 1);
        *(int4*)&rank[i] = r;
    } else {
        for (; i < E; ++i) rank[i] = atomicAdd(&counts[src[i]], 1);
    }
}

__global__ __launch_bounds__(256) void scan_reduce_kernel(const int* __restrict__ counts,
                                                          int* __restrict__ partials, int N)
{
    int t = threadIdx.x, lane = t & 63, wave = t >> 6;
    int base = blockIdx.x * 1024 + t * 4;
    int s = 0;
#pragma unroll
    for (int i = 0; i < 4; ++i)
        if (base + i < N) s += counts[base + i];
    for (int off = 32; off > 0; off >>= 1) s += __shfl_down(s, off);
    __shared__ int wsum[4];
    if (lane == 0) wsum[wave] = s;
    __syncthreads();
    if (t == 0) partials[blockIdx.x] = wsum[0] + wsum[1] + wsum[2] + wsum[3];
}

__global__ void scan_partials_kernel(int* __restrict__ p, int n)
{
    int lane = threadIdx.x & 63;
    int run = 0;
    for (int base = 0; base < n; base += 128) {
        int o0 = (base + lane      < n) ? p[base + lane]      : 0;
        int o1 = (base + 64 + lane < n) ? p[base + 64 + lane] : 0;
        int v0 = o0, v1 = o1;
        for (int off = 1; off < 64; off <<= 1) { int u = __shfl_up(v0, off); if (lane >= off) v0 += u; }
        int tot0 = __shfl(v0, 63);
        for (int off = 1; off < 64; off <<= 1) { int u = __shfl_up(v1, off); if (lane >= off) v1 += u; }
        v1 += tot0;
        int tot1 = __shfl(v1, 63);
        if (base + lane      < n) p[base + lane]      = run + v0 - o0;
        if (base + 64 + lane < n) p[base + 64 + lane] = run + v1 - o1;
        run += tot1;
    }
}

__global__ __launch_bounds__(256) void scan_final_kernel(const int* __restrict__ counts,
                                                         const int* __restrict__ partials,
                                                         int* __restrict__ row_start, int N)
{
    int t = threadIdx.x, lane = t & 63, wave = t >> 6;
    int base = blockIdx.x * 1024 + t * 4;
    int c0 = (base + 0 < N) ? counts[base + 0] : 0;
    int c1 = (base + 1 < N) ? counts[base + 1] : 0;
    int c2 = (base + 2 < N) ? counts[base + 2] : 0;
    int c3 = (base + 3 < N) ? counts[base + 3] : 0;
    int tsum = c0 + c1 + c2 + c3;
    int incl = tsum;
    for (int off = 1; off < 64; off <<= 1) { int u = __shfl_up(incl, off); if (lane >= off) incl += u; }
    __shared__ int wtot[4];
    if (lane == 63) wtot[wave] = incl;
    __syncthreads();
    int woff = 0;
    for (int w0 = 0; w0 < wave; ++w0) woff += wtot[w0];
    int run = incl - tsum + woff + partials[blockIdx.x];
    if (base + 0 < N) { row_start[base + 0] = run; run += c0; }
    if (base + 1 < N) { row_start[base + 1] = run; run += c1; }
    if (base + 2 < N) { row_start[base + 2] = run; run += c2; }
    if (base + 3 < N) { row_start[base + 3] = run; run += c3; }
}

// ---------------- scatter: no atomics; payload {dst, leaky(f1[src]+f2[dst])} ----------------
__global__ __launch_bounds__(256) void scatter_kernel(
    const int* __restrict__ src, const int* __restrict__ dst, const int* __restrict__ rank,
    const int* __restrict__ row_start, const float* __restrict__ f1, const float* __restrict__ f2,
    unsigned long long* __restrict__ csr8, int E)
{
    int e = blockIdx.x * 256 + threadIdx.x;
    if (e >= E) return;
    int s = src[e];
    int d = dst[e];
    int pos = row_start[s] + rank[e];
    float el = f1[s] + f2[d];
    el = (el > 0.f) ? el : LEAKY * el;
    unsigned long long u = (unsigned long long)(unsigned)d |
                           ((unsigned long long)__builtin_bit_cast(unsigned, el) << 32);
    csr8[pos] = u;
}

// ---------------- coef: one thread per node; softmax over its edges, rewrite payload ----------------
__global__ __launch_bounds__(256) void coef_kernel(
    const int* __restrict__ row_start, const int* __restrict__ counts,
    unsigned long long* __restrict__ csr8, int N)
{
    int n = blockIdx.x * 256 + threadIdx.x;
    if (n >= N) return;
    int base = row_start[n];
    int deg  = counts[n];
    float m = -INFINITY, den = 0.f;
    for (int i = 0; i < deg; ++i) {
        float e = __builtin_bit_cast(float, (unsigned)(csr8[base + i] >> 32));
        float mn = fmaxf(m, e);
        den = den * __expf(m - mn) + __expf(e - mn);
        m = mn;
    }
    if (deg <= 0) return;
    float rden = 1.f / den;
    for (int i = 0; i < deg; ++i) {
        unsigned long long u = csr8[base + i];
        float e = __builtin_bit_cast(float, (unsigned)(u >> 32));
        float c = __expf(e - m) * rden;
        csr8[base + i] = (u & 0xffffffffull) |
                         ((unsigned long long)__builtin_bit_cast(unsigned, c) << 32);
    }
}

// ---------------- aggregation: one wave per node; acc += coef * h[dst] ----------------
__global__ __launch_bounds__(256) void aggregate_kernel(
    const unsigned short* __restrict__ h2,
    const int* __restrict__ row_start, const int* __restrict__ counts,
    const unsigned long long* __restrict__ csr8, const float* __restrict__ out_bias,
    float* __restrict__ out, int N)
{
    int gw   = (blockIdx.x * 256 + threadIdx.x) >> 6;
    int lane = threadIdx.x & 63;
    if (gw >= N) return;
    int base = row_start[gw];
    int deg  = counts[gw];

    float acc = 0.f;
    int i = 0;
    for (; i + 4 <= deg; i += 4) {
        unsigned long long u0 = csr8[base + i + 0];
        unsigned long long u1 = csr8[base + i + 1];
        unsigned long long u2 = csr8[base + i + 2];
        unsigned long long u3 = csr8[base + i + 3];
        unsigned o0 = ((unsigned)u0 << 6) + lane;
        unsigned o1 = ((unsigned)u1 << 6) + lane;
        unsigned o2 = ((unsigned)u2 << 6) + lane;
        unsigned o3 = ((unsigned)u3 << 6) + lane;
        float hv0 = bf16bits_to_f32(h2[o0]);
        float hv1 = bf16bits_to_f32(h2[o1]);
        float hv2 = bf16bits_to_f32(h2[o2]);
        float hv3 = bf16bits_to_f32(h2[o3]);
        float c0 = __builtin_bit_cast(float, (unsigned)(u0 >> 32));
        float c1 = __builtin_bit_cast(float, (unsigned)(u1 >> 32));
        float c2 = __builtin_bit_cast(float, (unsigned)(u2 >> 32));
        float c3 = __builtin_bit_cast(float, (unsigned)(u3 >> 32));
        acc += c0 * hv0 + c1 * hv1 + c2 * hv2 + c3 * hv3;
    }
    for (; i < deg; ++i) {
        unsigned long long u = csr8[base + i];
        float hv = bf16bits_to_f32(h2[((unsigned)u << 6) + lane]);
        acc += __builtin_bit_cast(float, (unsigned)(u >> 32)) * hv;
    }
    float v = acc + out_bias[lane];
    out[((unsigned)gw << 6) + lane] = (v > 0.f) ? v : (__expf(v) - 1.f);
}

extern "C" void kernel_launch(void* const* d_in, const int* in_sizes, int n_in,
                              void* d_out, int out_size, void* d_ws, size_t ws_size,
                              hipStream_t stream)
{
    const float* x        = (const float*)d_in[0];
    const float* W        = (const float*)d_in[1];
    const float* a1       = (const float*)d_in[2];
    const float* b1       = (const float*)d_in[3];
    const float* a2       = (const float*)d_in[4];
    const float* b2       = (const float*)d_in[5];
    const float* out_bias = (const float*)d_in[6];
    const int*   esrc     = (const int*)d_in[7];
    const int*   edst     = (const int*)d_in[8];
    const int N = in_sizes[0] / F_IN;
    const int E = in_sizes[7];
    float* out = (float*)d_out;

    char* wsp = (char*)d_ws;
    size_t off = 0;
    auto alloc = [&](size_t bytes) -> void* {
        void* p = wsp + off;
        off = (off + bytes + 255) & ~(size_t)255;
        return p;
    };
    unsigned short* h2   = (unsigned short*)alloc((size_t)N * OUT * sizeof(unsigned short));
    float* f1            = (float*)alloc((size_t)N * sizeof(float));
    float* f2            = (float*)alloc((size_t)N * sizeof(float));
    int*   counts        = (int*)alloc((size_t)N * sizeof(int));
    int*   row_start     = (int*)alloc((size_t)N * sizeof(int));
    int*   rank          = (int*)alloc((size_t)E * sizeof(int));
    int    nsb           = (N + 1023) / 1024;
    int*   partials      = (int*)alloc((size_t)nsb * sizeof(int));
    unsigned long long* csr8 = (unsigned long long*)alloc((size_t)E * sizeof(unsigned long long));

    hipMemsetAsync(counts, 0, (size_t)N * sizeof(int), stream);

    count_rank_kernel<<<(E / 4 + 255) / 256, 256, 0, stream>>>(esrc, counts, rank, E);
    scan_reduce_kernel<<<nsb, 256, 0, stream>>>(counts, partials, N);
    scan_partials_kernel<<<1, 64, 0, stream>>>(partials, nsb);
    scan_final_kernel<<<nsb, 256, 0, stream>>>(counts, partials, row_start, N);
    gemm_f12_kernel<<<(N + 127) / 128, 256, 0, stream>>>(x, W, a1, b1, a2, b2, h2, f1, f2, N);
    scatter_kernel<<<(E + 255) / 256, 256, 0, stream>>>(esrc, edst, rank, row_start, f1, f2, csr8, E);
    coef_kernel<<<(N + 255) / 256, 256, 0, stream>>>(row_start, counts, csr8, N);
    aggregate_kernel<<<(N + 3) / 4, 256, 0, stream>>>(h2, row_start, counts, csr8,
                                                      out_bias, out, N);
}

// Round 6
// 176.187 us; speedup vs baseline: 1.3059x; 1.3059x over previous
//
#include <hip/hip_runtime.h>
#include <math.h>

#define F_IN 256
#define OUT  64
#define LEAKY 0.2f

typedef __attribute__((ext_vector_type(4))) float f32x4;
typedef __attribute__((ext_vector_type(8))) __bf16 bf16x8;
typedef __attribute__((ext_vector_type(4))) unsigned int u32x4;

__device__ __forceinline__ unsigned cvt_pk_bf16(float lo, float hi) {
    unsigned r;
    asm volatile("v_cvt_pk_bf16_f32 %0, %1, %2" : "=v"(r) : "v"(lo), "v"(hi));
    return r;
}

__device__ __forceinline__ float bf16bits_to_f32(unsigned short u) {
    return __builtin_bit_cast(float, (unsigned)u << 16);
}

__device__ __forceinline__ void gload_lds16(const float* g, float* l) {
    __builtin_amdgcn_global_load_lds((const __attribute__((address_space(1))) void*)g,
                                     (__attribute__((address_space(3))) void*)l, 16, 0, 0);
}

// ---------------- fused: MFMA GEMM blocks + count/rank blocks (1:2 interleave) ----------------
// bid%3==0 -> gemm block g=bid/3 (128 rows); else count block c=(bid/3)*2+(bid%3)-1 (1024 edges).
// gemm: h=x@W bf16-MFMA fp32-acc, fused f1/f2, h stored bf16.
// count: rank[e]=atomicAdd(&counts[src[e]],1)  (atomic-throughput-bound; overlaps gemm compute)
__global__ __launch_bounds__(256) void fused_gemm_count_kernel(
    const float* __restrict__ x, const float* __restrict__ W,
    const float* __restrict__ a1, const float* __restrict__ b1,
    const float* __restrict__ a2, const float* __restrict__ b2,
    unsigned short* __restrict__ h2, float* __restrict__ f1, float* __restrict__ f2,
    const int* __restrict__ esrc, int* __restrict__ counts, int* __restrict__ rank,
    int N, int E, int nCount)
{
    __shared__ __align__(16) unsigned int Wt[64 * 128];   // 32 KB
    __shared__ __align__(16) float xs[2][128 * 32];       // 32 KB

    const int bid  = blockIdx.x;
    const int t    = threadIdx.x;

    if (bid % 3 != 0) {
        // ---------------- count/rank path ----------------
        int c = (bid / 3) * 2 + (bid % 3) - 1;
        if (c >= nCount) return;
        int i = c * 1024 + t * 4;
        if (i + 4 <= E) {
            int4 s = *(const int4*)&esrc[i];
            int4 r;
            r.x = atomicAdd(&counts[s.x], 1);
            r.y = atomicAdd(&counts[s.y], 1);
            r.z = atomicAdd(&counts[s.z], 1);
            r.w = atomicAdd(&counts[s.w], 1);
            *(int4*)&rank[i] = r;
        } else {
            for (; i < E; ++i) rank[i] = atomicAdd(&counts[esrc[i]], 1);
        }
        return;
    }

    // ---------------- gemm path ----------------
    const int wave = t >> 6;
    const int lane = t & 63;
    const int rowB = (bid / 3) * 128;

    for (int p = t; p < 64 * 32; p += 256) {
        int c = p & 63, g = p >> 6;
        float f[8];
#pragma unroll
        for (int j = 0; j < 8; ++j) f[j] = W[(g * 8 + j) * 64 + c];
        u32x4 d;
        d.x = cvt_pk_bf16(f[0], f[1]);
        d.y = cvt_pk_bf16(f[2], f[3]);
        d.z = cvt_pk_bf16(f[4], f[5]);
        d.w = cvt_pk_bf16(f[6], f[7]);
        int gs = g ^ (c & 7);
        *(u32x4*)&Wt[c * 128 + gs * 4] = d;
    }

    auto stage = [&](int buf, int kc) {
#pragma unroll
        for (int i = 0; i < 4; ++i) {
            int row  = i * 32 + wave * 8 + (lane >> 3);
            int g    = lane & 7;
            int srow = rowB + row; if (srow > N - 1) srow = N - 1;
            int gsw  = g ^ (row & 7);
            const float* src = x + (size_t)srow * F_IN + kc + gsw * 4;
            gload_lds16(src, &xs[buf][i * 1024 + wave * 256]);
        }
    };

    f32x4 acc[2][4];
#pragma unroll
    for (int m = 0; m < 2; ++m)
#pragma unroll
        for (int n = 0; n < 4; ++n) acc[m][n] = (f32x4){0.f, 0.f, 0.f, 0.f};

    stage(0, 0);
    asm volatile("s_waitcnt vmcnt(0)" ::: "memory");
    __syncthreads();

    for (int ks = 0; ks < 8; ++ks) {
        int cur = ks & 1;
        if (ks < 7) stage(cur ^ 1, (ks + 1) * 32);

        bf16x8 bfrag[4];
#pragma unroll
        for (int ns = 0; ns < 4; ++ns) {
            int c = ns * 16 + (lane & 15);
            int G = ks * 4 + (lane >> 4);
            u32x4 bw = *(u32x4*)&Wt[c * 128 + ((G ^ (c & 7)) << 2)];
            bfrag[ns] = __builtin_bit_cast(bf16x8, bw);
        }
#pragma unroll
        for (int ms = 0; ms < 2; ++ms) {
            int wrow = wave * 32 + ms * 16 + (lane & 15);
            int g0   = (lane >> 4) * 2;
            float4 xa = *(float4*)&xs[cur][wrow * 32 + (((g0 + 0) ^ (wrow & 7)) << 2)];
            float4 xb = *(float4*)&xs[cur][wrow * 32 + (((g0 + 1) ^ (wrow & 7)) << 2)];
            u32x4 ad;
            ad.x = cvt_pk_bf16(xa.x, xa.y);
            ad.y = cvt_pk_bf16(xa.z, xa.w);
            ad.z = cvt_pk_bf16(xb.x, xb.y);
            ad.w = cvt_pk_bf16(xb.z, xb.w);
            bf16x8 afrag = __builtin_bit_cast(bf16x8, ad);
#pragma unroll
            for (int ns = 0; ns < 4; ++ns)
                acc[ms][ns] = __builtin_amdgcn_mfma_f32_16x16x32_bf16(afrag, bfrag[ns],
                                                                      acc[ms][ns], 0, 0, 0);
        }
        asm volatile("s_waitcnt vmcnt(0)" ::: "memory");
        __syncthreads();
    }

    float A1v[4], A2v[4];
#pragma unroll
    for (int ns = 0; ns < 4; ++ns) {
        A1v[ns] = a1[ns * 16 + (lane & 15)];
        A2v[ns] = a2[ns * 16 + (lane & 15)];
    }
    float B1 = b1[0], B2 = b2[0];
#pragma unroll
    for (int ms = 0; ms < 2; ++ms) {
#pragma unroll
        for (int r = 0; r < 4; ++r) {
            int grow = rowB + wave * 32 + ms * 16 + ((lane >> 4) << 2) + r;
            float s1 = 0.f, s2 = 0.f;
#pragma unroll
            for (int ns = 0; ns < 4; ++ns) {
                float v = acc[ms][ns][r];
                if (grow < N)
                    h2[(size_t)grow * OUT + ns * 16 + (lane & 15)] =
                        (unsigned short)(cvt_pk_bf16(v, v) & 0xffffu);
                s1 += v * A1v[ns];
                s2 += v * A2v[ns];
            }
#pragma unroll
            for (int off = 1; off < 16; off <<= 1) {
                s1 += __shfl_xor(s1, off);
                s2 += __shfl_xor(s2, off);
            }
            if ((lane & 15) == 0 && grow < N) { f1[grow] = s1 + B1; f2[grow] = s2 + B2; }
        }
    }
}

// ---------------- scan ----------------
__global__ __launch_bounds__(256) void scan_reduce_kernel(const int* __restrict__ counts,
                                                          int* __restrict__ partials, int N)
{
    int t = threadIdx.x, lane = t & 63, wave = t >> 6;
    int base = blockIdx.x * 1024 + t * 4;
    int s = 0;
#pragma unroll
    for (int i = 0; i < 4; ++i)
        if (base + i < N) s += counts[base + i];
    for (int off = 32; off > 0; off >>= 1) s += __shfl_down(s, off);
    __shared__ int wsum[4];
    if (lane == 0) wsum[wave] = s;
    __syncthreads();
    if (t == 0) partials[blockIdx.x] = wsum[0] + wsum[1] + wsum[2] + wsum[3];
}

__global__ void scan_partials_kernel(int* __restrict__ p, int n)
{
    int lane = threadIdx.x & 63;
    int run = 0;
    for (int base = 0; base < n; base += 128) {
        int o0 = (base + lane      < n) ? p[base + lane]      : 0;
        int o1 = (base + 64 + lane < n) ? p[base + 64 + lane] : 0;
        int v0 = o0, v1 = o1;
        for (int off = 1; off < 64; off <<= 1) { int u = __shfl_up(v0, off); if (lane >= off) v0 += u; }
        int tot0 = __shfl(v0, 63);
        for (int off = 1; off < 64; off <<= 1) { int u = __shfl_up(v1, off); if (lane >= off) v1 += u; }
        v1 += tot0;
        int tot1 = __shfl(v1, 63);
        if (base + lane      < n) p[base + lane]      = run + v0 - o0;
        if (base + 64 + lane < n) p[base + 64 + lane] = run + v1 - o1;
        run += tot1;
    }
}

__global__ __launch_bounds__(256) void scan_final_kernel(const int* __restrict__ counts,
                                                         const int* __restrict__ partials,
                                                         int* __restrict__ row_start, int N)
{
    int t = threadIdx.x, lane = t & 63, wave = t >> 6;
    int base = blockIdx.x * 1024 + t * 4;
    int c0 = (base + 0 < N) ? counts[base + 0] : 0;
    int c1 = (base + 1 < N) ? counts[base + 1] : 0;
    int c2 = (base + 2 < N) ? counts[base + 2] : 0;
    int c3 = (base + 3 < N) ? counts[base + 3] : 0;
    int tsum = c0 + c1 + c2 + c3;
    int incl = tsum;
    for (int off = 1; off < 64; off <<= 1) { int u = __shfl_up(incl, off); if (lane >= off) incl += u; }
    __shared__ int wtot[4];
    if (lane == 63) wtot[wave] = incl;
    __syncthreads();
    int woff = 0;
    for (int w0 = 0; w0 < wave; ++w0) woff += wtot[w0];
    int run = incl - tsum + woff + partials[blockIdx.x];
    if (base + 0 < N) { row_start[base + 0] = run; run += c0; }
    if (base + 1 < N) { row_start[base + 1] = run; run += c1; }
    if (base + 2 < N) { row_start[base + 2] = run; run += c2; }
    if (base + 3 < N) { row_start[base + 3] = run; run += c3; }
}

// ---------------- scatter: no atomics; payload {dst, f2[dst]} ----------------
__global__ __launch_bounds__(256) void scatter_kernel(
    const int* __restrict__ src, const int* __restrict__ dst, const int* __restrict__ rank,
    const int* __restrict__ row_start, const float* __restrict__ f2,
    unsigned long long* __restrict__ csr8, int E)
{
    int e = blockIdx.x * 256 + threadIdx.x;
    if (e >= E) return;
    int s = src[e];
    int d = dst[e];
    int pos = row_start[s] + rank[e];
    unsigned long long u = (unsigned long long)(unsigned)d |
                           ((unsigned long long)__builtin_bit_cast(unsigned, f2[d]) << 32);
    csr8[pos] = u;
}

// ---------------- aggregation: one wave per node ----------------
// phase A (lane-per-edge): coalesced csr8 read, leaky, wave-softmax via shfl_xor (once/64 edges)
// phase B (lane-per-feature): broadcast {p,d} via shfl, gather h row, acc += p*h
__global__ __launch_bounds__(256) void aggregate_kernel(
    const unsigned short* __restrict__ h2, const float* __restrict__ f1,
    const int* __restrict__ row_start, const int* __restrict__ counts,
    const unsigned long long* __restrict__ csr8, const float* __restrict__ out_bias,
    float* __restrict__ out, int N)
{
    int gw   = (blockIdx.x * 256 + threadIdx.x) >> 6;
    int lane = threadIdx.x & 63;
    if (gw >= N) return;
    int base = row_start[gw];
    int deg  = counts[gw];
    float f1n = f1[gw];

    float m = -INFINITY, den = 0.f, acc = 0.f;

    for (int c0 = 0; c0 < deg; c0 += 64) {
        int  idx   = c0 + lane;
        bool valid = idx < deg;
        unsigned long long u = valid ? csr8[base + idx] : 0ull;
        int   d = (int)(unsigned)u;
        float e = f1n + __builtin_bit_cast(float, (unsigned)(u >> 32));
        e = (e > 0.f) ? e : LEAKY * e;
        if (!valid) e = -INFINITY;

        float cm = e;
#pragma unroll
        for (int off = 1; off < 64; off <<= 1) cm = fmaxf(cm, __shfl_xor(cm, off));
        float mn = fmaxf(m, cm);
        float sc = __expf(m - mn);              // 0 on first chunk (m=-inf)
        float p  = __expf(e - mn);              // 0 for invalid lanes
        float sp = p;
#pragma unroll
        for (int off = 1; off < 64; off <<= 1) sp += __shfl_xor(sp, off);
        den = den * sc + sp;
        acc *= sc;
        m = mn;

        int lim = deg - c0; if (lim > 64) lim = 64;
        int j = 0;
        for (; j + 4 <= lim; j += 4) {
            float p0 = __shfl(p, j + 0), p1 = __shfl(p, j + 1);
            float p2 = __shfl(p, j + 2), p3 = __shfl(p, j + 3);
            int   d0 = __shfl(d, j + 0), d1 = __shfl(d, j + 1);
            int   d2 = __shfl(d, j + 2), d3 = __shfl(d, j + 3);
            float h0 = bf16bits_to_f32(h2[((unsigned)d0 << 6) + lane]);
            float h1 = bf16bits_to_f32(h2[((unsigned)d1 << 6) + lane]);
            float h3v = bf16bits_to_f32(h2[((unsigned)d3 << 6) + lane]);
            float h2v = bf16bits_to_f32(h2[((unsigned)d2 << 6) + lane]);
            acc += p0 * h0 + p1 * h1 + p2 * h2v + p3 * h3v;
        }
        for (; j < lim; ++j) {
            float pj = __shfl(p, j);
            int   dj = __shfl(d, j);
            acc += pj * bf16bits_to_f32(h2[((unsigned)dj << 6) + lane]);
        }
    }

    float v = (deg > 0) ? (acc / den) : 0.f;
    v += out_bias[lane];
    out[((unsigned)gw << 6) + lane] = (v > 0.f) ? v : (__expf(v) - 1.f);
}

extern "C" void kernel_launch(void* const* d_in, const int* in_sizes, int n_in,
                              void* d_out, int out_size, void* d_ws, size_t ws_size,
                              hipStream_t stream)
{
    const float* x        = (const float*)d_in[0];
    const float* W        = (const float*)d_in[1];
    const float* a1       = (const float*)d_in[2];
    const float* b1       = (const float*)d_in[3];
    const float* a2       = (const float*)d_in[4];
    const float* b2       = (const float*)d_in[5];
    const float* out_bias = (const float*)d_in[6];
    const int*   esrc     = (const int*)d_in[7];
    const int*   edst     = (const int*)d_in[8];
    const int N = in_sizes[0] / F_IN;
    const int E = in_sizes[7];
    float* out = (float*)d_out;

    char* wsp = (char*)d_ws;
    size_t off = 0;
    auto alloc = [&](size_t bytes) -> void* {
        void* p = wsp + off;
        off = (off + bytes + 255) & ~(size_t)255;
        return p;
    };
    unsigned short* h2   = (unsigned short*)alloc((size_t)N * OUT * sizeof(unsigned short));
    float* f1            = (float*)alloc((size_t)N * sizeof(float));
    float* f2            = (float*)alloc((size_t)N * sizeof(float));
    int*   counts        = (int*)alloc((size_t)N * sizeof(int));
    int*   row_start     = (int*)alloc((size_t)N * sizeof(int));
    int*   rank          = (int*)alloc((size_t)E * sizeof(int));
    int    nsb           = (N + 1023) / 1024;
    int*   partials      = (int*)alloc((size_t)nsb * sizeof(int));
    unsigned long long* csr8 = (unsigned long long*)alloc((size_t)E * sizeof(unsigned long long));

    hipMemsetAsync(counts, 0, (size_t)N * sizeof(int), stream);

    int gemmBlocks  = (N + 127) / 128;             // 782
    int countBlocks = (E + 1023) / 1024;           // 1563
    int totalBlocks = gemmBlocks * 3;              // 1:2 interleave covers 2*gemmBlocks count slots
    fused_gemm_count_kernel<<<totalBlocks, 256, 0, stream>>>(
        x, W, a1, b1, a2, b2, h2, f1, f2, esrc, counts, rank, N, E, countBlocks);
    scan_reduce_kernel<<<nsb, 256, 0, stream>>>(counts, partials, N);
    scan_partials_kernel<<<1, 64, 0, stream>>>(partials, nsb);
    scan_final_kernel<<<nsb, 256, 0, stream>>>(counts, partials, row_start, N);
    scatter_kernel<<<(E + 255) / 256, 256, 0, stream>>>(esrc, edst, rank, row_start, f2, csr8, E);
    aggregate_kernel<<<(N + 3) / 4, 256, 0, stream>>>(h2, f1, row_start, counts, csr8,
                                                      out_bias, out, N);
}